// Round 2
// baseline (4435.409 us; speedup 1.0000x reference)
//
#include <hip/hip_runtime.h>
#include <hip/hip_bf16.h>
#include <cstdint>
#include <cstddef>

#define HIDDEN 4096
#define INTER  16384
#define NTOK   8192   // 4*2048 tokens
#define LN_EPS 1e-5f

typedef unsigned short u16;
typedef u16   u16x8 __attribute__((ext_vector_type(8)));
typedef u16   u16x4 __attribute__((ext_vector_type(4)));
typedef __bf16 bf16x8 __attribute__((ext_vector_type(8)));
typedef float  f32x4 __attribute__((ext_vector_type(4)));

__device__ __forceinline__ u16 f2bf(float f) {
    union { float f; unsigned int ui; } x;
    x.f = f;
    unsigned int u = x.ui;
    unsigned int r = (u + 0x7FFFu + ((u >> 16) & 1u)) >> 16;  // round-nearest-even
    return (u16)r;
}

__device__ __forceinline__ void gl_lds16(const u16* g, u16* l) {
    __builtin_amdgcn_global_load_lds(
        (const __attribute__((address_space(1))) void*)g,
        (__attribute__((address_space(3))) void*)l,
        16, 0, 0);
}

// ---------------------------------------------------------------------------
// Cast fp32 [K,N] -> bf16 [N,K] (transpose). Tile 64x64 via LDS.
// Grid: (N/64, K/64).
// ---------------------------------------------------------------------------
#define TDIM 64
__global__ __launch_bounds__(256) void cvt_transpose(const float* __restrict__ in,
                                                     u16* __restrict__ out,
                                                     int K, int N) {
    __shared__ float tile[TDIM][TDIM + 1];
    const int bn = blockIdx.x * TDIM;
    const int bk = blockIdx.y * TDIM;
    const int t  = threadIdx.x;
#pragma unroll
    for (int it = 0; it < 4; ++it) {
        int idx = it * 256 + t;        // 0..1023
        int r = idx >> 4;              // 0..63  (k within tile)
        int c = (idx & 15) * 4;        // 0..60  (n within tile)
        const float4 v = *(const float4*)(in + (size_t)(bk + r) * N + bn + c);
        tile[r][c]     = v.x;
        tile[r][c + 1] = v.y;
        tile[r][c + 2] = v.z;
        tile[r][c + 3] = v.w;
    }
    __syncthreads();
#pragma unroll
    for (int it = 0; it < 2; ++it) {
        int idx = it * 256 + t;        // 0..511
        int r = idx >> 3;              // 0..63  (n within tile)
        int c = (idx & 7) * 8;         // 0..56  (k within tile)
        u16x8 o;
#pragma unroll
        for (int j = 0; j < 8; ++j) o[j] = f2bf(tile[c + j][r]);
        *(u16x8*)(out + (size_t)(bn + r) * K + bk + c) = o;
    }
}

// ---------------------------------------------------------------------------
// res = input + residual + bias; ln = bf16(LN(res)*gamma + beta).
// One block (256 thr) per token row. fp32 in, bf16 out.
// ---------------------------------------------------------------------------
__global__ __launch_bounds__(256) void fused_add_ln(const float* __restrict__ in,
                                                    const float* __restrict__ resid,
                                                    const float* __restrict__ bias,
                                                    const float* __restrict__ gamma,
                                                    const float* __restrict__ beta,
                                                    u16* __restrict__ out) {
    const int row = blockIdx.x;
    const size_t base = (size_t)row * HIDDEN;
    const int t = threadIdx.x;
    const int c0 = t * 16;                 // 16 elems/thread (4096/256)
    float v[16];
    float s = 0.f, s2 = 0.f;
#pragma unroll
    for (int g = 0; g < 4; ++g) {
        float4 vi = *(const float4*)(in    + base + c0 + g * 4);
        float4 vr = *(const float4*)(resid + base + c0 + g * 4);
        float4 vb = *(const float4*)(bias  + c0 + g * 4);
        float xs[4] = {vi.x + vr.x + vb.x, vi.y + vr.y + vb.y,
                       vi.z + vr.z + vb.z, vi.w + vr.w + vb.w};
#pragma unroll
        for (int j = 0; j < 4; ++j) {
            float x = xs[j];
            v[g * 4 + j] = x;
            s += x;
            s2 += x * x;
        }
    }
#pragma unroll
    for (int off = 32; off > 0; off >>= 1) {
        s  += __shfl_down(s, off, 64);
        s2 += __shfl_down(s2, off, 64);
    }
    __shared__ float sred[4], s2red[4], stats[2];
    const int wave = t >> 6, lane = t & 63;
    if (lane == 0) { sred[wave] = s; s2red[wave] = s2; }
    __syncthreads();
    if (t == 0) {
        float ts  = sred[0] + sred[1] + sred[2] + sred[3];
        float ts2 = s2red[0] + s2red[1] + s2red[2] + s2red[3];
        float mean = ts * (1.0f / HIDDEN);
        float var  = ts2 * (1.0f / HIDDEN) - mean * mean;
        stats[0] = mean;
        stats[1] = rsqrtf(var + LN_EPS);
    }
    __syncthreads();
    const float mean = stats[0], rstd = stats[1];
#pragma unroll
    for (int g = 0; g < 2; ++g) {
        u16x8 o;
#pragma unroll
        for (int j = 0; j < 8; ++j) {
            int e = g * 8 + j;
            float gm = gamma[c0 + e];
            float bt = beta[c0 + e];
            o[j] = f2bf((v[e] - mean) * rstd * gm + bt);
        }
        *(u16x8*)(out + base + c0 + g * 8) = o;
    }
}

// ---------------------------------------------------------------------------
// GEMM: C[M,N] = A[M,K] * BT[N,K]^T, bf16 in, fp32 accum.
// m97 structure: 128x128 tile, 4 waves (2x2 of 64x64), 16x16x32 MFMA, BK=32,
// global_load_lds width-16 staging, 2-barrier K-loop.
// EPI==0: Cb = bf16(gelu_tanh(acc + b0f[col]))
// EPI==1: Cf = acc + in_f[m,n] + res_f[m,n] + b0f[col] + b1f[col]   (fp32 out)
// ---------------------------------------------------------------------------
template <int EPI>
__global__ __launch_bounds__(256) void gemm_bt(const u16* __restrict__ A,
                                               const u16* __restrict__ BT,
                                               u16* __restrict__ Cb,
                                               float* __restrict__ Cf,
                                               const float* __restrict__ b0f,
                                               const float* __restrict__ b1f,
                                               const float* __restrict__ in_f,
                                               const float* __restrict__ res_f,
                                               int M, int N, int K) {
    __shared__ u16 As[128 * 32];
    __shared__ u16 Bs[128 * 32];
    const int t    = threadIdx.x;
    const int wave = t >> 6;
    const int lane = t & 63;
    const int l16  = lane & 15;
    const int quad = lane >> 4;
    const int m0 = blockIdx.y * 128;
    const int n0 = blockIdx.x * 128;
    const int wm = (wave >> 1) * 64;
    const int wn = (wave & 1) * 64;

    f32x4 acc[4][4];
#pragma unroll
    for (int i = 0; i < 4; ++i)
#pragma unroll
        for (int j = 0; j < 4; ++j)
            acc[i][j] = f32x4{0.f, 0.f, 0.f, 0.f};

    for (int k0 = 0; k0 < K; k0 += 32) {
        // Stage A (128x32) and B (128x32): 512 16B-chunks each, 2/thread.
#pragma unroll
        for (int it = 0; it < 2; ++it) {
            int idx = it * 256 + t;
            int row = idx >> 2;            // 0..127
            int ce  = (idx & 3) * 8;       // 0,8,16,24
            int ldsoff = (it * 256 + wave * 64) * 8;  // wave-uniform chunk base
            gl_lds16(A  + (size_t)(m0 + row) * K + k0 + ce, As + ldsoff);
            gl_lds16(BT + (size_t)(n0 + row) * K + k0 + ce, Bs + ldsoff);
        }
        __syncthreads();

        bf16x8 af[4], bfr[4];
#pragma unroll
        for (int i = 0; i < 4; ++i)
            af[i] = *(const bf16x8*)(As + (wm + i * 16 + l16) * 32 + quad * 8);
#pragma unroll
        for (int j = 0; j < 4; ++j)
            bfr[j] = *(const bf16x8*)(Bs + (wn + j * 16 + l16) * 32 + quad * 8);
#pragma unroll
        for (int i = 0; i < 4; ++i)
#pragma unroll
            for (int j = 0; j < 4; ++j)
                acc[i][j] = __builtin_amdgcn_mfma_f32_16x16x32_bf16(af[i], bfr[j], acc[i][j], 0, 0, 0);
        __syncthreads();
    }

    // Epilogue.  C/D layout: col = lane&15, row = quad*4 + r.
#pragma unroll
    for (int i = 0; i < 4; ++i) {
#pragma unroll
        for (int j = 0; j < 4; ++j) {
            const int col = n0 + wn + j * 16 + l16;
#pragma unroll
            for (int r = 0; r < 4; ++r) {
                const int rowi = m0 + wm + i * 16 + quad * 4 + r;
                float x = acc[i][j][r];
                if (EPI == 0) {
                    x += b0f[col];
                    // gelu_tanh(x) = x * sigmoid(2*0.7978845608*(x + 0.044715 x^3))
                    float u  = 0.7978845608f * (x + 0.044715f * x * x * x);
                    float sg = 1.0f / (1.0f + __expf(-2.0f * u));
                    Cb[(size_t)rowi * N + col] = f2bf(x * sg);
                } else {
                    size_t off = (size_t)rowi * N + col;
                    Cf[off] = x + in_f[off] + res_f[off] + b0f[col] + b1f[col];
                }
            }
        }
    }
}

// ---------------------------------------------------------------------------
extern "C" void kernel_launch(void* const* d_in, const int* in_sizes, int n_in,
                              void* d_out, int out_size, void* d_ws, size_t ws_size,
                              hipStream_t stream) {
    const float* input    = (const float*)d_in[0];
    const float* residual = (const float*)d_in[1];
    // d_in[2] residual_norm: unused by the reference path
    const float* bias     = (const float*)d_in[3];
    const float* attn_nw  = (const float*)d_in[4];
    const float* attn_nb  = (const float*)d_in[5];
    const float* inter_w  = (const float*)d_in[6];   // [HIDDEN, INTER] fp32
    const float* inter_b  = (const float*)d_in[7];
    const float* output_w = (const float*)d_in[8];   // [INTER, HIDDEN] fp32
    const float* output_b = (const float*)d_in[9];
    float* out = (float*)d_out;

    char* ws = (char*)d_ws;
    u16* w1t   = (u16*)(ws);                    // bf16 [INTER, HIDDEN]  128MB
    u16* w2t   = (u16*)(ws + 134217728);        // bf16 [HIDDEN, INTER]  128MB
    u16* ln    = (u16*)(ws + 268435456);        // bf16 [NTOK, HIDDEN]    64MB
    u16* inter = (u16*)(ws + 335544320);        // bf16 [NTOK, INTER]    256MB

    cvt_transpose<<<dim3(INTER / TDIM, HIDDEN / TDIM), 256, 0, stream>>>(inter_w, w1t, HIDDEN, INTER);
    cvt_transpose<<<dim3(HIDDEN / TDIM, INTER / TDIM), 256, 0, stream>>>(output_w, w2t, INTER, HIDDEN);
    fused_add_ln<<<NTOK, 256, 0, stream>>>(input, residual, bias, attn_nw, attn_nb, ln);
    gemm_bt<0><<<dim3(INTER / 128, NTOK / 128), 256, 0, stream>>>(
        ln, w1t, inter, nullptr, inter_b, nullptr, nullptr, nullptr, NTOK, INTER, HIDDEN);
    gemm_bt<1><<<dim3(HIDDEN / 128, NTOK / 128), 256, 0, stream>>>(
        inter, w2t, nullptr, out, bias, output_b, input, residual, NTOK, HIDDEN, INTER);
}